// Round 6
// baseline (212.395 us; speedup 1.0000x reference)
//
#include <hip/hip_runtime.h>
#include <math.h>

#define NSMP 48
#define FSTR 72    // feat row stride in f16 (72 data; 144B rows, 16B-aligned)
#define HSTR 72    // hid row stride in f16

typedef _Float16 f16;
typedef _Float16 half8 __attribute__((ext_vector_type(8)));
typedef _Float16 half4 __attribute__((ext_vector_type(4)));
typedef _Float16 h2    __attribute__((ext_vector_type(2)));
typedef float    f32x4 __attribute__((ext_vector_type(4)));

__device__ __forceinline__ float sigmoid_f(float x){
    return __builtin_amdgcn_rcpf(1.0f + __expf(-x));
}
// fast f16 gelu: Phi-table indexed by top-10 bits of the f16 value (sign+exp+4 mant)
__device__ __forceinline__ h2 gelu16x2(h2 x, const f16* __restrict__ lut16){
    const uint32_t w = __builtin_bit_cast(uint32_t, x);
    h2 m = { lut16[(w>>6) & 0x3FF], lut16[w>>22] };
    return x * m;
}
__device__ __forceinline__ f16 gelu16_1(f16 x, const f16* __restrict__ lut16){
    const uint16_t w = __builtin_bit_cast(uint16_t, x);
    return x * lut16[(w>>6) & 0x3FF];
}

// Block = ONE ray, 4 waves:
//   waves 0..2: gather mode wv (phase 1), m-tile wv of GEMM1/GEMM2, then EXIT after barrier 3
//   wave  3   : PE fold during gather, m-tile 3 of GEMM1/GEMM2, ALL of phase 5 (3 n-tiles,
//               shfl redistribution instead of LDS), volume integration. Barrier 4 removed.
//
// TR layouts (built by fused_prep):
//   mats16: [ib][c4(4)][qy(24)][qx(24)][sy(2)][sx(2)][8ch]
//           64B line = 2x2 pixel quad x 8ch (adjacent samples share quads -> low
//           per-instruction unique-line scatter); c4 planes 73KB apart (channel spread).
//   vecs16: [ib][c4(4)][row(48)][8ch]  (whole c4-plane = 12 lines; c4 stride 768B = imm offset)
//   wT    : frag-ordered [wv(4)][ks(3)][lane(64)][8]   (A-frag read = coalesced 1KB)
//   w1T   : frag-ordered [wv(4)][ks(2)][lane(64)][8]
//   w2T16 : frag-ordered [ks(2)][lane(64)][8]
template<bool TR>
__global__ __launch_bounds__(256, 8)
void render_kernel(const float* __restrict__ rays_o,
                   const float* __restrict__ rays_d,
                   const f16*   __restrict__ mats16,
                   const f16*   __restrict__ vecs16,
                   const float* __restrict__ matsf,   // !TR: original f32 layout
                   const float* __restrict__ vecsf,
                   const f16*   __restrict__ wTf,
                   const float* __restrict__ g_bmat,
                   const f16*   __restrict__ w1f,
                   const float* __restrict__ g_b1,
                   const float* __restrict__ g_w1,    // f32 w1 (PE rows 64..90)
                   const f16*   __restrict__ w2f,
                   const float* __restrict__ g_b2,
                   const f16*   __restrict__ g_lut,   // [1024] f16 Phi table (from prep)
                   float* __restrict__ out, int B, int R)
{
    __shared__ __align__(16) f16   s_feat[NSMP*FSTR];   // 6912 B  feat (then gelu(h2) overlay)
    __shared__ __align__(16) f16   s_hid [NSMP*HSTR];   // 6912 B  gelu(hid)
    __shared__ __align__(16) f16   s_lut16[1024];       // 2048 B
    __shared__ float s_pe[64];                          //  256 B
    __shared__ float s_sig[3][NSMP];                    //  576 B  -> 16704 B total

    const int tid  = threadIdx.x;
    const int wv   = tid >> 6;
    const int lane = tid & 63;
    const int NR   = B*R;
    const int ray  = blockIdx.x;          // one block per ray, grid == NR
    const int b    = ray / R;

    // LUT: cooperative 2KB copy from global (precomputed in prep)
    ((half4*)s_lut16)[tid] = ((const half4*)g_lut)[tid];
    __syncthreads();                                        // barrier 0: LUT ready
    const f16* lut16 = s_lut16;

    const float dx=rays_d[ray*3+0], dy=rays_d[ray*3+1], dz=rays_d[ray*3+2];

    const int q  = lane >> 4;   // quad
    const int cl = lane & 15;   // col index within tile
    const int s  = lane;        // sample index (phases 1 & 6)
    const bool active = (s < NSMP);
    const int  sc     = active ? s : (NSMP-1);

    // ================= Phase 1: gather (wave = mode, lane = sample) =================
    if (wv < 3){
        const float ox=rays_o[ray*3+0], oy=rays_o[ray*3+1], oz=rays_o[ray*3+2];
        const int i = wv;
        const float midc = ((float)sc + 0.5f) * 0.03125f;
        const float x0c = 1.25f*(ox + dx*midc);
        const float x1c = 1.25f*(oy + dy*midc);
        const float x2c = 1.25f*(oz + dz*midc);

        // MAT_MODE = {{0,1},{2,0},{1,2}}, VEC_MODE = {2,1,0}
        const float cx = (i==0)? x0c : (i==1)? x2c : x1c;
        const float cy = (i==0)? x1c : (i==1)? x0c : x2c;
        const float cv = (i==0)? x2c : (i==1)? x1c : x0c;

        const float px = (cx+1.0f)*23.5f;
        const float py = (cy+1.0f)*23.5f;
        const float fx0 = floorf(px), fy0 = floorf(py);
        const float wx = px-fx0, wy = py-fy0;
        const int x0i = (int)fx0, y0i = (int)fy0;
        const int x1i = x0i+1,   y1i = y0i+1;

        // hoisted per-axis clamp + in-bounds
        const int  xc0 = min(max(x0i,0),47), xc1 = min(max(x1i,0),47);
        const int  yc0 = min(max(y0i,0),47), yc1 = min(max(y1i,0),47);
        const bool bx0 = (unsigned)x0i < 48u, bx1 = (unsigned)x1i < 48u;
        const bool by0 = (unsigned)y0i < 48u, by1 = (unsigned)y1i < 48u;
        const float wx1 = wx, wx0 = 1.0f-wx;
        const float wy1 = wy, wy0 = 1.0f-wy;

        float tw[4];
        tw[0] = (bx0&&by0)? wx0*wy0 : 0.0f;
        tw[1] = (bx1&&by0)? wx1*wy0 : 0.0f;
        tw[2] = (bx0&&by1)? wx0*wy1 : 0.0f;
        tw[3] = (bx1&&by1)? wx1*wy1 : 0.0f;

        // per-axis f16-offset terms for the c4-major tiled layout:
        //   off(c4=0) = (qy*24+qx)*32 + sy*16 + sx*8   (f16 units)
        const int rt0 = (yc0>>1)*768 + (yc0&1)*16;
        const int rt1 = (yc1>>1)*768 + (yc1&1)*16;
        const int ct0 = (xc0>>1)*32  + (xc0&1)*8;
        const int ct1 = (xc1>>1)*32  + (xc1&1)*8;

        // !TR linear pixel ids
        int toff[4];
        toff[0] = yc0*48+xc0; toff[1] = yc0*48+xc1;
        toff[2] = yc1*48+xc0; toff[3] = yc1*48+xc1;

        const float pv = (cv+1.0f)*23.5f;
        const float fp0 = floorf(pv);
        const float wvv = pv-fp0;
        const int ip0 = (int)fp0;
        int voff[2]; float vw[2];
        #pragma unroll
        for (int t=0;t<2;t++){
            const int pp = ip0+t;
            const bool inb = (unsigned)pp < 48u;
            voff[t] = min(max(pp,0),47);
            vw[t] = inb ? ((t)? wvv : 1.0f-wvv) : 0.0f;
        }

        float sigma = 0.0f;

        if (TR){
            const f16* pb = mats16 + ((size_t)(i*B+b))*(2304u*32u);
            const f16* vb = vecs16 + ((size_t)(i*B+b))*(48u*32u);
            const half8* t0 = (const half8*)(pb + rt0 + ct0);
            const half8* t1 = (const half8*)(pb + rt0 + ct1);
            const half8* t2 = (const half8*)(pb + rt1 + ct0);
            const half8* t3 = (const half8*)(pb + rt1 + ct1);
            const half8* v0 = (const half8*)(vb + voff[0]*8);
            const half8* v1 = (const half8*)(vb + voff[1]*8);

            const h2 tw0h = {(f16)tw[0],(f16)tw[0]};
            const h2 tw1h = {(f16)tw[1],(f16)tw[1]};
            const h2 tw2h = {(f16)tw[2],(f16)tw[2]};
            const h2 tw3h = {(f16)tw[3],(f16)tw[3]};
            const h2 vw0h = {(f16)vw[0],(f16)vw[0]};
            const h2 vw1h = {(f16)vw[1],(f16)vw[1]};

            #pragma unroll 2
            for (int c4=0;c4<4;c4++){
                // plane: c4 stride = 24*24*4 = 2304 half8 (73728B, channel-spread)
                // vec:   [c4][row][8ch] -> c4 stride 48 half8 = 768B imm offset
                const half8 a0=t0[c4*2304], a1=t1[c4*2304], a2=t2[c4*2304], a3=t3[c4*2304];
                const half8 q0=v0[c4*48], q1=v1[c4*48];
                h2 gg[4];
                #pragma unroll
                for (int j=0;j<4;j++){
                    const h2 a0j = {a0[2*j], a0[2*j+1]};
                    const h2 a1j = {a1[2*j], a1[2*j+1]};
                    const h2 a2j = {a2[2*j], a2[2*j+1]};
                    const h2 a3j = {a3[2*j], a3[2*j+1]};
                    const h2 q0j = {q0[2*j], q0[2*j+1]};
                    const h2 q1j = {q1[2*j], q1[2*j+1]};
                    h2 pf = a0j*tw0h; pf += a1j*tw1h; pf += a2j*tw2h; pf += a3j*tw3h;
                    h2 vf = q0j*vw0h; vf += q1j*vw1h;
                    const h2 fj = pf*vf;
                    if (c4==0){
                        sigma += (float)fj[0] + (float)fj[1];
                    } else {
                        gg[j] = gelu16x2(fj, lut16);
                    }
                }
                if (c4>0 && active){
                    half8 hv = {gg[0][0],gg[0][1],gg[1][0],gg[1][1],
                                gg[2][0],gg[2][1],gg[3][0],gg[3][1]};
                    *(half8*)(s_feat + s*FSTR + i*24 + c4*8 - 8) = hv;
                }
            }
        } else {
            const float* pb = matsf + ((size_t)(i*B+b))*(32u*2304u);
            const float* vb = vecsf + ((size_t)(i*B+b))*(32u*48u);
            #pragma unroll 2
            for (int c=0;c<32;c++){
                const float* fc = pb + c*2304;
                const float pf = tw[0]*fc[toff[0]] + tw[1]*fc[toff[1]]
                               + tw[2]*fc[toff[2]] + tw[3]*fc[toff[3]];
                const float* vc = vb + c*48;
                const float vf = vw[0]*vc[voff[0]] + vw[1]*vc[voff[1]];
                const float r = pf*vf;
                if (c < 8) sigma += r;
                else if (active) s_feat[s*FSTR + i*24 + c - 8] = gelu16_1((f16)r, lut16);
            }
        }
        if (active) s_sig[wv][s] = sigma;
    } else {
        // ================= Phase 3: PE fold (lane = hidden j), overlapped with gather ====
        float pe = g_b1[lane];
        const float inv_n = rsqrtf(dx*dx+dy*dy+dz*dz);
        const float vd0=dx*inv_n, vd1=dy*inv_n, vd2=dz*inv_n;
        pe += vd0*g_w1[64*64+lane] + vd1*g_w1[65*64+lane] + vd2*g_w1[66*64+lane];
        #pragma unroll 1
        for (int fq=0; fq<4; fq++){
            const float fs = (float)(1<<fq);
            float s0,c0,s1,c1,s2,c2;
            __sincosf(vd0*fs, &s0, &c0);
            __sincosf(vd1*fs, &s1, &c1);
            __sincosf(vd2*fs, &s2, &c2);
            pe += s0*g_w1[(67+fq*3+0)*64+lane];
            pe += s1*g_w1[(67+fq*3+1)*64+lane];
            pe += s2*g_w1[(67+fq*3+2)*64+lane];
            pe += c0*g_w1[(79+fq*3+0)*64+lane];
            pe += c1*g_w1[(79+fq*3+1)*64+lane];
            pe += c2*g_w1[(79+fq*3+2)*64+lane];
        }
        s_pe[lane] = pe;
    }
    __syncthreads();                                        // barrier 1: feat + pe + sig ready

    // ======== Phase 2: layer-1 GEMM  hid^T(64x48) = wT(64x96) @ feat^T(96x48), mt = wv ====
    {
        f32x4 acc[3];
        const float4 bmv = *(const float4*)(g_bmat + wv*16 + q*4);
        #pragma unroll
        for (int nt=0;nt<3;nt++){
            acc[nt][0]=bmv.x; acc[nt][1]=bmv.y; acc[nt][2]=bmv.z; acc[nt][3]=bmv.w;
        }
        #pragma unroll 1
        for (int ks=0; ks<2; ks++){
            half8 bf[3];
            #pragma unroll
            for (int nt=0;nt<3;nt++)
                bf[nt] = *(const half8*)(s_feat + (nt*16+cl)*FSTR + ks*32 + q*8);
            const half8 af = *(const half8*)(wTf + (((wv*3 + ks)*64 + lane)<<3));
            #pragma unroll
            for (int nt=0;nt<3;nt++)
                acc[nt] = __builtin_amdgcn_mfma_f32_16x16x32_f16(af, bf[nt], acc[nt], 0,0,0);
        }
        {   // ks=2: only q==0 holds real B data (k=64..71); wT rows k>=72 are zero-padded.
            half8 bf[3] = {{0,0,0,0,0,0,0,0},{0,0,0,0,0,0,0,0},{0,0,0,0,0,0,0,0}};
            if (q == 0){
                #pragma unroll
                for (int nt=0;nt<3;nt++)
                    bf[nt] = *(const half8*)(s_feat + (nt*16+cl)*FSTR + 64);
            }
            const half8 af = *(const half8*)(wTf + (((wv*3 + 2)*64 + lane)<<3));
            #pragma unroll
            for (int nt=0;nt<3;nt++)
                acc[nt] = __builtin_amdgcn_mfma_f32_16x16x32_f16(af, bf[nt], acc[nt], 0,0,0);
        }
        // gelu + store hid^T into s_hid (separate buffer -> no WAR barrier needed)
        #pragma unroll
        for (int nt=0;nt<3;nt++){
            const h2 p01 = __builtin_bit_cast(h2,
                __builtin_amdgcn_cvt_pkrtz(acc[nt][0], acc[nt][1]));
            const h2 p23 = __builtin_bit_cast(h2,
                __builtin_amdgcn_cvt_pkrtz(acc[nt][2], acc[nt][3]));
            const h2 g01 = gelu16x2(p01, lut16);
            const h2 g23 = gelu16x2(p23, lut16);
            half4 hv = {g01[0], g01[1], g23[0], g23[1]};
            *(half4*)(s_hid + (nt*16+cl)*HSTR + wv*16 + q*4) = hv;
        }
    }
    __syncthreads();                                        // barrier 2: hid ready

    // ======== Phase 4: layer-2 GEMM  h2^T(64x48) = w1T(64x64) @ hid^T(64x48), mt = wv ====
    {
        f32x4 acc2[3];
        const float4 pv4 = *(const float4*)&s_pe[wv*16 + q*4];
        #pragma unroll
        for (int nt=0;nt<3;nt++){
            acc2[nt][0]=pv4.x; acc2[nt][1]=pv4.y; acc2[nt][2]=pv4.z; acc2[nt][3]=pv4.w;
        }
        #pragma unroll 1
        for (int ks=0; ks<2; ks++){
            half8 bf[3];
            #pragma unroll
            for (int nt=0;nt<3;nt++)
                bf[nt] = *(const half8*)(s_hid + (nt*16+cl)*HSTR + ks*32 + q*8);
            const half8 af = *(const half8*)(w1f + (((wv*2 + ks)*64 + lane)<<3));
            #pragma unroll
            for (int nt=0;nt<3;nt++)
                acc2[nt] = __builtin_amdgcn_mfma_f32_16x16x32_f16(af, bf[nt], acc2[nt], 0,0,0);
        }
        // gelu(h2) -> overlay into s_feat (feat is dead after barrier 2; all waves past it)
        #pragma unroll
        for (int nt=0;nt<3;nt++){
            const h2 p01 = __builtin_bit_cast(h2,
                __builtin_amdgcn_cvt_pkrtz(acc2[nt][0], acc2[nt][1]));
            const h2 p23 = __builtin_bit_cast(h2,
                __builtin_amdgcn_cvt_pkrtz(acc2[nt][2], acc2[nt][3]));
            const h2 g01 = gelu16x2(p01, lut16);
            const h2 g23 = gelu16x2(p23, lut16);
            half4 hv = {g01[0], g01[1], g23[0], g23[1]};
            *(half4*)(s_feat + (nt*16+cl)*FSTR + wv*16 + q*4) = hv;
        }
    }
    __syncthreads();                                        // barrier 3: gelu(h2) ready

    if (wv < 3) return;   // waves 0..2 retire early; no further barriers in the block

    // ======== Phase 5 (wave 3 only): rgb^T(16x48) = w2T16(16x64) @ gelu(h2)^T, all 3 nt ====
    const float b20=g_b2[0], b21=g_b2[1], b22=g_b2[2];
    f32x4 acc3[3];
    #pragma unroll
    for (int nt=0;nt<3;nt++){
        acc3[nt][0] = (q==0)? b20 : 0.0f;
        acc3[nt][1] = (q==0)? b21 : 0.0f;
        acc3[nt][2] = (q==0)? b22 : 0.0f;
        acc3[nt][3] = 0.0f;
    }
    #pragma unroll 1
    for (int ks=0; ks<2; ks++){
        const half8 af = *(const half8*)(w2f + ((ks*64 + lane)<<3));
        #pragma unroll
        for (int nt=0;nt<3;nt++){
            const half8 bf = *(const half8*)(s_feat + (nt*16+cl)*FSTR + ks*32 + q*8);
            acc3[nt] = __builtin_amdgcn_mfma_f32_16x16x32_f16(af, bf, acc3[nt], 0,0,0);
        }
    }

    // redistribute within wave 3: lane L's sample rgb sits in lane (L&15) of tile (L>>4), rows 0..2
    float rgb0, rgb1, rgb2;
    {
        float t[3];
        #pragma unroll
        for (int r=0;r<3;r++){
            const float u0 = __shfl(acc3[0][r], cl, 64);
            const float u1 = __shfl(acc3[1][r], cl, 64);
            const float u2 = __shfl(acc3[2][r], cl, 64);
            t[r] = (q==0)? u0 : (q==1)? u1 : u2;
        }
        rgb0 = sigmoid_f(t[0]);
        rgb1 = sigmoid_f(t[1]);
        rgb2 = sigmoid_f(t[2]);
    }

    // ======== Phase 6 (wave 3): volume integration (lane = sample) ========
    {
        const float mid = ((float)s + 0.5f) * 0.03125f;
        const float sgs = s_sig[0][sc] + s_sig[1][sc] + s_sig[2][sc];
        const float sg  = fmaxf(sgs, 0.0f);

        const float alpha = active ? (1.0f - __expf(-sg*0.03125f)) : 0.0f;
        float v = active ? (1.0f - alpha + 1e-10f) : 1.0f;
        #pragma unroll
        for (int off=1; off<64; off<<=1){
            const float up = __shfl_up(v, off, 64);
            if (lane >= off) v *= up;
        }
        float T = __shfl_up(v, 1, 64);
        if (lane==0) T = 1.0f;
        const float w = alpha*T;

        if (active) out[(size_t)NR*4 + (size_t)ray*NSMP + s] = w;

        float A0=w*rgb0, A1=w*rgb1, A2=w*rgb2, AD=w*mid;
        #pragma unroll
        for (int off=32; off>0; off>>=1){
            A0 += __shfl_down(A0, off, 64);
            A1 += __shfl_down(A1, off, 64);
            A2 += __shfl_down(A2, off, 64);
            AD += __shfl_down(AD, off, 64);
        }
        if (lane==0){
            out[(size_t)ray*3+0]=A0;
            out[(size_t)ray*3+1]=A1;
            out[(size_t)ray*3+2]=A2;
            out[(size_t)NR*3 + (size_t)ray]=AD;
        }
    }
}

// One fused prep kernel:
//  blocks [0, tileN)          : LDS-tiled mats transpose f32 [ib][32][2304] -> c4-major quad-tiled f16
//  blocks [tileN, tileN+prepN): vec regroup + frag-ordered weight prep + gelu Phi LUT
__global__ __launch_bounds__(256)
void fused_prep(const float* __restrict__ mats, const float* __restrict__ vecs,
                const float* __restrict__ w_mat, const float* __restrict__ w1,
                const float* __restrict__ w2,
                f16* __restrict__ tm, f16* __restrict__ tv,
                f16* __restrict__ wT, f16* __restrict__ w1T, f16* __restrict__ w2T16,
                f16* __restrict__ lut,
                int tileN, int vecsz){
    __shared__ float tl[32][33];
    const int bid = blockIdx.x;
    if (bid < tileN){
        const int ib   = bid / 72;
        const int pix0 = (bid % 72) * 32;
        const int tx = threadIdx.x & 31;
        const int ty = threadIdx.x >> 5;      // 0..7
        const float* src = mats + (size_t)ib*32*2304;
        #pragma unroll
        for (int t=0;t<4;t++){
            const int c = ty + t*8;
            tl[c][tx] = src[(size_t)c*2304 + pix0 + tx];
        }
        __syncthreads();
        f16* dst = tm + (size_t)ib*2304*32;
        #pragma unroll
        for (int t=0;t<4;t++){
            const int p  = pix0 + ty + t*8;   // global pixel id
            const int y  = p / 48, x = p % 48;
            const int c  = tx;                 // channel
            // [c4][qy][qx][sy][sx][8ch]
            const int o  = ((((c>>3)*24 + (y>>1))*24 + (x>>1))*4 + (y&1)*2 + (x&1))*8 + (c&7);
            dst[o] = (f16)tl[tx][ty + t*8];
        }
    } else {
        const int idx = (bid - tileN)*256 + threadIdx.x;
        if (idx < vecsz){
            // src: idx = (ib*32 + c)*48 + r  ->  dst [ib][c4][r][8ch]
            const int r  = idx % 48;
            const int c  = (idx / 48) & 31;
            const int ib = idx / (48*32);
            tv[(((size_t)ib*4 + (c>>3))*48 + r)*8 + (c&7)] = (f16)vecs[idx];
        } else if (idx < vecsz + 64*96){
            // frag-ordered wT: [(wv*3+ks)*64 + lane]*8 + e
            const int i1   = idx - vecsz;
            const int e    = i1 & 7;
            const int lane = (i1 >> 3) & 63;
            const int t    = i1 >> 9;          // 0..11
            const int ks   = t % 3;
            const int wvv  = t / 3;
            const int n = wvv*16 + (lane & 15);
            const int k = ks*32 + (lane >> 4)*8 + e;
            wT[i1] = (k < 72) ? (f16)w_mat[k*64+n] : (f16)0.0f;
        } else if (idx < vecsz + 64*96 + 64*64){
            // frag-ordered w1T: [(wv*2+ks)*64 + lane]*8 + e
            const int i2   = idx - vecsz - 64*96;
            const int e    = i2 & 7;
            const int lane = (i2 >> 3) & 63;
            const int t    = i2 >> 9;          // 0..7
            const int ks   = t & 1;
            const int wvv  = t >> 1;
            const int n = wvv*16 + (lane & 15);
            const int k = ks*32 + (lane >> 4)*8 + e;
            w1T[i2] = (f16)w1[k*64+n];
        } else if (idx < vecsz + 64*96 + 64*64 + 16*64){
            // frag-ordered w2T16: [ks*64 + lane]*8 + e
            const int i3   = idx - vecsz - 64*96 - 64*64;
            const int e    = i3 & 7;
            const int lane = (i3 >> 3) & 63;
            const int ks   = i3 >> 9;          // 0..1
            const int n = lane & 15;
            const int k = ks*32 + (lane >> 4)*8 + e;
            w2T16[i3] = (n < 3) ? (f16)w2[k*3+n] : (f16)0.0f;
        } else if (idx < vecsz + 64*96 + 64*64 + 16*64 + 1024){
            const int i4 = idx - vecsz - 64*96 - 64*64 - 16*64;
            const unsigned short bits = (unsigned short)((i4<<6) | 0x20);  // bin midpoint
            const f16 xh = __builtin_bit_cast(f16, bits);
            float m;
            if (((i4>>4)&0x1F) == 31) m = (i4 & 0x200) ? 0.0f : 1.0f;      // inf/nan bins
            else {
                const float x = (float)xh;
                m = 0.5f*(1.0f + erff(x*0.70710678118654752f));            // Phi(x)
            }
            lut[i4] = (f16)m;
        }
    }
}

extern "C" void kernel_launch(void* const* d_in, const int* in_sizes, int n_in,
                              void* d_out, int out_size, void* d_ws, size_t ws_size,
                              hipStream_t stream) {
    const float* rays_o  = (const float*)d_in[0];
    const float* rays_d  = (const float*)d_in[1];
    const float* matrixs = (const float*)d_in[2];
    const float* vectors = (const float*)d_in[3];
    const float* w_mat   = (const float*)d_in[4];
    const float* b_mat   = (const float*)d_in[5];
    const float* w1      = (const float*)d_in[6];
    const float* b1      = (const float*)d_in[7];
    const float* w2      = (const float*)d_in[8];
    const float* b2      = (const float*)d_in[9];
    float* out = (float*)d_out;

    const int B = in_sizes[2] / (3*32*48*48);
    const int R = (in_sizes[0]/3) / B;
    const int NR = B*R;

    const int matsz = 3*B*32*2304;
    const int vecsz = 3*B*32*48;
    const int wtot  = 64*96 + 64*64 + 16*64 + 1024;     // weights + Phi LUT
    const size_t need_full = ((size_t)matsz + (size_t)vecsz + (size_t)wtot)*sizeof(f16);
    const size_t need_w    = (size_t)wtot*sizeof(f16);

    const int nblk = NR;            // one block (4 waves) per ray
    const int nthr = 256;

    if (ws_size >= need_full){
        f16* tm    = (f16*)d_ws;
        f16* tv    = tm + matsz;
        f16* wT    = tv + vecsz;
        f16* w1T   = wT + 64*96;
        f16* w2T16 = w1T + 64*64;
        f16* lut   = w2T16 + 16*64;
        const int tileN = 72*3*B;
        const int smalln = vecsz + wtot;
        const int prepN  = (smalln + 255)/256;
        fused_prep<<<tileN + prepN, 256, 0, stream>>>(matrixs, vectors, w_mat, w1, w2,
                                                      tm, tv, wT, w1T, w2T16, lut, tileN, vecsz);
        render_kernel<true><<<nblk, nthr, 0, stream>>>(rays_o, rays_d, tm, tv,
            nullptr, nullptr, wT, b_mat, w1T, b1, w1, w2T16, b2, lut, out, B, R);
    } else if (ws_size >= need_w){
        f16* wT    = (f16*)d_ws;
        f16* w1T   = wT + 64*96;
        f16* w2T16 = w1T + 64*64;
        f16* lut   = w2T16 + 16*64;
        const int prepN = (wtot + 255)/256;
        fused_prep<<<prepN, 256, 0, stream>>>(nullptr, nullptr, w_mat, w1, w2,
                                              nullptr, nullptr, wT, w1T, w2T16, lut, 0, 0);
        render_kernel<false><<<nblk, nthr, 0, stream>>>(rays_o, rays_d,
            nullptr, nullptr, matrixs, vectors, wT, b_mat, w1T, b1, w1, w2T16, b2, lut, out, B, R);
    }
}

// Round 7
// 200.030 us; speedup vs baseline: 1.0618x; 1.0618x over previous
//
#include <hip/hip_runtime.h>
#include <math.h>

#define NSMP 48
#define FSTR 72    // feat row stride in f16 (72 data; 144B rows, 16B-aligned)
#define HSTR 72    // hid row stride in f16

typedef _Float16 f16;
typedef _Float16 half8 __attribute__((ext_vector_type(8)));
typedef _Float16 half4 __attribute__((ext_vector_type(4)));
typedef _Float16 h2    __attribute__((ext_vector_type(2)));
typedef float    f32x4 __attribute__((ext_vector_type(4)));

__device__ __forceinline__ float sigmoid_f(float x){
    return __builtin_amdgcn_rcpf(1.0f + __expf(-x));
}
// fast f16 gelu: Phi-table indexed by top-10 bits of the f16 value (sign+exp+4 mant)
__device__ __forceinline__ h2 gelu16x2(h2 x, const f16* __restrict__ lut16){
    const uint32_t w = __builtin_bit_cast(uint32_t, x);
    h2 m = { lut16[(w>>6) & 0x3FF], lut16[w>>22] };
    return x * m;
}
__device__ __forceinline__ f16 gelu16_1(f16 x, const f16* __restrict__ lut16){
    const uint16_t w = __builtin_bit_cast(uint16_t, x);
    return x * lut16[(w>>6) & 0x3FF];
}

// Block = ONE ray, 4 waves:
//   waves 0..2: gather mode wv (phase 1), m-tile wv of GEMM1/GEMM2, then EXIT after barrier 3
//   wave  3   : PE fold during gather, m-tile 3 of GEMM1/GEMM2, ALL of phase 5 (3 n-tiles,
//               shfl redistribution instead of LDS), volume integration. Barrier 4 removed.
//
// TR layouts (built by fused_prep):
//   mats16: [ib][c4(4)][qy(24)][qx(24)][sy(2)][sx(2)][8ch]
//           64B line = 2x2 pixel quad x 8ch (adjacent samples share quads -> low
//           per-instruction unique-line scatter); c4 planes 73KB apart (channel spread).
//   vecs16: [ib][c4(4)][row(48)][8ch]  (whole c4-plane = 12 lines; c4 stride 768B = imm offset)
//   wT    : frag-ordered [wv(4)][ks(3)][lane(64)][8]   (A-frag read = coalesced 1KB)
//   w1T   : frag-ordered [wv(4)][ks(2)][lane(64)][8]
//   w2T16 : frag-ordered [ks(2)][lane(64)][8]
//
// Gather c4-loop is software-pipelined (1-iter-ahead rotating prefetch, +24 VGPR) so the
// 6 global loads of iteration c4+1 are in flight while iteration c4's blend executes.
template<bool TR>
__global__ __launch_bounds__(256, 8)
void render_kernel(const float* __restrict__ rays_o,
                   const float* __restrict__ rays_d,
                   const f16*   __restrict__ mats16,
                   const f16*   __restrict__ vecs16,
                   const float* __restrict__ matsf,   // !TR: original f32 layout
                   const float* __restrict__ vecsf,
                   const f16*   __restrict__ wTf,
                   const float* __restrict__ g_bmat,
                   const f16*   __restrict__ w1f,
                   const float* __restrict__ g_b1,
                   const float* __restrict__ g_w1,    // f32 w1 (PE rows 64..90)
                   const f16*   __restrict__ w2f,
                   const float* __restrict__ g_b2,
                   const f16*   __restrict__ g_lut,   // [1024] f16 Phi table (from prep)
                   float* __restrict__ out, int B, int R)
{
    __shared__ __align__(16) f16   s_feat[NSMP*FSTR];   // 6912 B  feat (then gelu(h2) overlay)
    __shared__ __align__(16) f16   s_hid [NSMP*HSTR];   // 6912 B  gelu(hid)
    __shared__ __align__(16) f16   s_lut16[1024];       // 2048 B
    __shared__ float s_pe[64];                          //  256 B
    __shared__ float s_sig[3][NSMP];                    //  576 B  -> 16704 B total

    const int tid  = threadIdx.x;
    const int wv   = tid >> 6;
    const int lane = tid & 63;
    const int NR   = B*R;
    const int ray  = blockIdx.x;          // one block per ray, grid == NR
    const int b    = ray / R;

    // LUT: cooperative 2KB copy from global (precomputed in prep)
    ((half4*)s_lut16)[tid] = ((const half4*)g_lut)[tid];
    __syncthreads();                                        // barrier 0: LUT ready
    const f16* lut16 = s_lut16;

    const float dx=rays_d[ray*3+0], dy=rays_d[ray*3+1], dz=rays_d[ray*3+2];

    const int q  = lane >> 4;   // quad
    const int cl = lane & 15;   // col index within tile
    const int s  = lane;        // sample index (phases 1 & 6)
    const bool active = (s < NSMP);
    const int  sc     = active ? s : (NSMP-1);

    // ================= Phase 1: gather (wave = mode, lane = sample) =================
    if (wv < 3){
        const float ox=rays_o[ray*3+0], oy=rays_o[ray*3+1], oz=rays_o[ray*3+2];
        const int i = wv;
        const float midc = ((float)sc + 0.5f) * 0.03125f;
        const float x0c = 1.25f*(ox + dx*midc);
        const float x1c = 1.25f*(oy + dy*midc);
        const float x2c = 1.25f*(oz + dz*midc);

        // MAT_MODE = {{0,1},{2,0},{1,2}}, VEC_MODE = {2,1,0}
        const float cx = (i==0)? x0c : (i==1)? x2c : x1c;
        const float cy = (i==0)? x1c : (i==1)? x0c : x2c;
        const float cv = (i==0)? x2c : (i==1)? x1c : x0c;

        const float px = (cx+1.0f)*23.5f;
        const float py = (cy+1.0f)*23.5f;
        const float fx0 = floorf(px), fy0 = floorf(py);
        const float wx = px-fx0, wy = py-fy0;
        const int x0i = (int)fx0, y0i = (int)fy0;
        const int x1i = x0i+1,   y1i = y0i+1;

        // hoisted per-axis clamp + in-bounds
        const int  xc0 = min(max(x0i,0),47), xc1 = min(max(x1i,0),47);
        const int  yc0 = min(max(y0i,0),47), yc1 = min(max(y1i,0),47);
        const bool bx0 = (unsigned)x0i < 48u, bx1 = (unsigned)x1i < 48u;
        const bool by0 = (unsigned)y0i < 48u, by1 = (unsigned)y1i < 48u;
        const float wx1 = wx, wx0 = 1.0f-wx;
        const float wy1 = wy, wy0 = 1.0f-wy;

        float tw[4];
        tw[0] = (bx0&&by0)? wx0*wy0 : 0.0f;
        tw[1] = (bx1&&by0)? wx1*wy0 : 0.0f;
        tw[2] = (bx0&&by1)? wx0*wy1 : 0.0f;
        tw[3] = (bx1&&by1)? wx1*wy1 : 0.0f;

        // per-axis f16-offset terms for the c4-major tiled layout:
        //   off(c4=0) = (qy*24+qx)*32 + sy*16 + sx*8   (f16 units)
        const int rt0 = (yc0>>1)*768 + (yc0&1)*16;
        const int rt1 = (yc1>>1)*768 + (yc1&1)*16;
        const int ct0 = (xc0>>1)*32  + (xc0&1)*8;
        const int ct1 = (xc1>>1)*32  + (xc1&1)*8;

        // !TR linear pixel ids
        int toff[4];
        toff[0] = yc0*48+xc0; toff[1] = yc0*48+xc1;
        toff[2] = yc1*48+xc0; toff[3] = yc1*48+xc1;

        const float pv = (cv+1.0f)*23.5f;
        const float fp0 = floorf(pv);
        const float wvv = pv-fp0;
        const int ip0 = (int)fp0;
        int voff[2]; float vw[2];
        #pragma unroll
        for (int t=0;t<2;t++){
            const int pp = ip0+t;
            const bool inb = (unsigned)pp < 48u;
            voff[t] = min(max(pp,0),47);
            vw[t] = inb ? ((t)? wvv : 1.0f-wvv) : 0.0f;
        }

        float sigma = 0.0f;

        if (TR){
            const f16* pb = mats16 + ((size_t)(i*B+b))*(2304u*32u);
            const f16* vb = vecs16 + ((size_t)(i*B+b))*(48u*32u);
            const half8* t0 = (const half8*)(pb + rt0 + ct0);
            const half8* t1 = (const half8*)(pb + rt0 + ct1);
            const half8* t2 = (const half8*)(pb + rt1 + ct0);
            const half8* t3 = (const half8*)(pb + rt1 + ct1);
            const half8* v0 = (const half8*)(vb + voff[0]*8);
            const half8* v1 = (const half8*)(vb + voff[1]*8);

            const h2 tw0h = {(f16)tw[0],(f16)tw[0]};
            const h2 tw1h = {(f16)tw[1],(f16)tw[1]};
            const h2 tw2h = {(f16)tw[2],(f16)tw[2]};
            const h2 tw3h = {(f16)tw[3],(f16)tw[3]};
            const h2 vw0h = {(f16)vw[0],(f16)vw[0]};
            const h2 vw1h = {(f16)vw[1],(f16)vw[1]};

            // software-pipelined c4 loop: prefetch iteration c4+1's 6 loads
            // (plane c4 stride = 2304 half8 = 73728B; vec c4 stride = 48 half8 = 768B)
            half8 a0 = t0[0], a1 = t1[0], a2 = t2[0], a3 = t3[0];
            half8 q0 = v0[0], q1 = v1[0];
            #pragma unroll
            for (int c4=0;c4<4;c4++){
                half8 na0,na1,na2,na3,nq0,nq1;
                if (c4 < 3){
                    na0 = t0[(c4+1)*2304]; na1 = t1[(c4+1)*2304];
                    na2 = t2[(c4+1)*2304]; na3 = t3[(c4+1)*2304];
                    nq0 = v0[(c4+1)*48];   nq1 = v1[(c4+1)*48];
                }
                h2 gg[4];
                #pragma unroll
                for (int j=0;j<4;j++){
                    const h2 a0j = {a0[2*j], a0[2*j+1]};
                    const h2 a1j = {a1[2*j], a1[2*j+1]};
                    const h2 a2j = {a2[2*j], a2[2*j+1]};
                    const h2 a3j = {a3[2*j], a3[2*j+1]};
                    const h2 q0j = {q0[2*j], q0[2*j+1]};
                    const h2 q1j = {q1[2*j], q1[2*j+1]};
                    h2 pf = a0j*tw0h; pf += a1j*tw1h; pf += a2j*tw2h; pf += a3j*tw3h;
                    h2 vf = q0j*vw0h; vf += q1j*vw1h;
                    const h2 fj = pf*vf;
                    if (c4==0){
                        sigma += (float)fj[0] + (float)fj[1];
                    } else {
                        gg[j] = gelu16x2(fj, lut16);
                    }
                }
                if (c4>0 && active){
                    half8 hv = {gg[0][0],gg[0][1],gg[1][0],gg[1][1],
                                gg[2][0],gg[2][1],gg[3][0],gg[3][1]};
                    *(half8*)(s_feat + s*FSTR + i*24 + c4*8 - 8) = hv;
                }
                if (c4 < 3){
                    a0=na0; a1=na1; a2=na2; a3=na3; q0=nq0; q1=nq1;
                }
            }
        } else {
            const float* pb = matsf + ((size_t)(i*B+b))*(32u*2304u);
            const float* vb = vecsf + ((size_t)(i*B+b))*(32u*48u);
            #pragma unroll 2
            for (int c=0;c<32;c++){
                const float* fc = pb + c*2304;
                const float pf = tw[0]*fc[toff[0]] + tw[1]*fc[toff[1]]
                               + tw[2]*fc[toff[2]] + tw[3]*fc[toff[3]];
                const float* vc = vb + c*48;
                const float vf = vw[0]*vc[voff[0]] + vw[1]*vc[voff[1]];
                const float r = pf*vf;
                if (c < 8) sigma += r;
                else if (active) s_feat[s*FSTR + i*24 + c - 8] = gelu16_1((f16)r, lut16);
            }
        }
        if (active) s_sig[wv][s] = sigma;
    } else {
        // ================= Phase 3: PE fold (lane = hidden j), overlapped with gather ====
        float pe = g_b1[lane];
        const float inv_n = rsqrtf(dx*dx+dy*dy+dz*dz);
        const float vd0=dx*inv_n, vd1=dy*inv_n, vd2=dz*inv_n;
        pe += vd0*g_w1[64*64+lane] + vd1*g_w1[65*64+lane] + vd2*g_w1[66*64+lane];
        #pragma unroll 1
        for (int fq=0; fq<4; fq++){
            const float fs = (float)(1<<fq);
            float s0,c0,s1,c1,s2,c2;
            __sincosf(vd0*fs, &s0, &c0);
            __sincosf(vd1*fs, &s1, &c1);
            __sincosf(vd2*fs, &s2, &c2);
            pe += s0*g_w1[(67+fq*3+0)*64+lane];
            pe += s1*g_w1[(67+fq*3+1)*64+lane];
            pe += s2*g_w1[(67+fq*3+2)*64+lane];
            pe += c0*g_w1[(79+fq*3+0)*64+lane];
            pe += c1*g_w1[(79+fq*3+1)*64+lane];
            pe += c2*g_w1[(79+fq*3+2)*64+lane];
        }
        s_pe[lane] = pe;
    }
    __syncthreads();                                        // barrier 1: feat + pe + sig ready

    // ======== Phase 2: layer-1 GEMM  hid^T(64x48) = wT(64x96) @ feat^T(96x48), mt = wv ====
    {
        f32x4 acc[3];
        const float4 bmv = *(const float4*)(g_bmat + wv*16 + q*4);
        #pragma unroll
        for (int nt=0;nt<3;nt++){
            acc[nt][0]=bmv.x; acc[nt][1]=bmv.y; acc[nt][2]=bmv.z; acc[nt][3]=bmv.w;
        }
        #pragma unroll 1
        for (int ks=0; ks<2; ks++){
            half8 bf[3];
            #pragma unroll
            for (int nt=0;nt<3;nt++)
                bf[nt] = *(const half8*)(s_feat + (nt*16+cl)*FSTR + ks*32 + q*8);
            const half8 af = *(const half8*)(wTf + (((wv*3 + ks)*64 + lane)<<3));
            #pragma unroll
            for (int nt=0;nt<3;nt++)
                acc[nt] = __builtin_amdgcn_mfma_f32_16x16x32_f16(af, bf[nt], acc[nt], 0,0,0);
        }
        {   // ks=2: only q==0 holds real B data (k=64..71); wT rows k>=72 are zero-padded.
            half8 bf[3] = {{0,0,0,0,0,0,0,0},{0,0,0,0,0,0,0,0},{0,0,0,0,0,0,0,0}};
            if (q == 0){
                #pragma unroll
                for (int nt=0;nt<3;nt++)
                    bf[nt] = *(const half8*)(s_feat + (nt*16+cl)*FSTR + 64);
            }
            const half8 af = *(const half8*)(wTf + (((wv*3 + 2)*64 + lane)<<3));
            #pragma unroll
            for (int nt=0;nt<3;nt++)
                acc[nt] = __builtin_amdgcn_mfma_f32_16x16x32_f16(af, bf[nt], acc[nt], 0,0,0);
        }
        // gelu + store hid^T into s_hid (separate buffer -> no WAR barrier needed)
        #pragma unroll
        for (int nt=0;nt<3;nt++){
            const h2 p01 = __builtin_bit_cast(h2,
                __builtin_amdgcn_cvt_pkrtz(acc[nt][0], acc[nt][1]));
            const h2 p23 = __builtin_bit_cast(h2,
                __builtin_amdgcn_cvt_pkrtz(acc[nt][2], acc[nt][3]));
            const h2 g01 = gelu16x2(p01, lut16);
            const h2 g23 = gelu16x2(p23, lut16);
            half4 hv = {g01[0], g01[1], g23[0], g23[1]};
            *(half4*)(s_hid + (nt*16+cl)*HSTR + wv*16 + q*4) = hv;
        }
    }
    __syncthreads();                                        // barrier 2: hid ready

    // ======== Phase 4: layer-2 GEMM  h2^T(64x48) = w1T(64x64) @ hid^T(64x48), mt = wv ====
    {
        f32x4 acc2[3];
        const float4 pv4 = *(const float4*)&s_pe[wv*16 + q*4];
        #pragma unroll
        for (int nt=0;nt<3;nt++){
            acc2[nt][0]=pv4.x; acc2[nt][1]=pv4.y; acc2[nt][2]=pv4.z; acc2[nt][3]=pv4.w;
        }
        #pragma unroll 1
        for (int ks=0; ks<2; ks++){
            half8 bf[3];
            #pragma unroll
            for (int nt=0;nt<3;nt++)
                bf[nt] = *(const half8*)(s_hid + (nt*16+cl)*HSTR + ks*32 + q*8);
            const half8 af = *(const half8*)(w1f + (((wv*2 + ks)*64 + lane)<<3));
            #pragma unroll
            for (int nt=0;nt<3;nt++)
                acc2[nt] = __builtin_amdgcn_mfma_f32_16x16x32_f16(af, bf[nt], acc2[nt], 0,0,0);
        }
        // gelu(h2) -> overlay into s_feat (feat is dead after barrier 2; all waves past it)
        #pragma unroll
        for (int nt=0;nt<3;nt++){
            const h2 p01 = __builtin_bit_cast(h2,
                __builtin_amdgcn_cvt_pkrtz(acc2[nt][0], acc2[nt][1]));
            const h2 p23 = __builtin_bit_cast(h2,
                __builtin_amdgcn_cvt_pkrtz(acc2[nt][2], acc2[nt][3]));
            const h2 g01 = gelu16x2(p01, lut16);
            const h2 g23 = gelu16x2(p23, lut16);
            half4 hv = {g01[0], g01[1], g23[0], g23[1]};
            *(half4*)(s_feat + (nt*16+cl)*FSTR + wv*16 + q*4) = hv;
        }
    }
    __syncthreads();                                        // barrier 3: gelu(h2) ready

    if (wv < 3) return;   // waves 0..2 retire early; no further barriers in the block

    // ======== Phase 5 (wave 3 only): rgb^T(16x48) = w2T16(16x64) @ gelu(h2)^T, all 3 nt ====
    const float b20=g_b2[0], b21=g_b2[1], b22=g_b2[2];
    f32x4 acc3[3];
    #pragma unroll
    for (int nt=0;nt<3;nt++){
        acc3[nt][0] = (q==0)? b20 : 0.0f;
        acc3[nt][1] = (q==0)? b21 : 0.0f;
        acc3[nt][2] = (q==0)? b22 : 0.0f;
        acc3[nt][3] = 0.0f;
    }
    #pragma unroll 1
    for (int ks=0; ks<2; ks++){
        const half8 af = *(const half8*)(w2f + ((ks*64 + lane)<<3));
        #pragma unroll
        for (int nt=0;nt<3;nt++){
            const half8 bf = *(const half8*)(s_feat + (nt*16+cl)*FSTR + ks*32 + q*8);
            acc3[nt] = __builtin_amdgcn_mfma_f32_16x16x32_f16(af, bf, acc3[nt], 0,0,0);
        }
    }

    // redistribute within wave 3: lane L's sample rgb sits in lane (L&15) of tile (L>>4), rows 0..2
    float rgb0, rgb1, rgb2;
    {
        float t[3];
        #pragma unroll
        for (int r=0;r<3;r++){
            const float u0 = __shfl(acc3[0][r], cl, 64);
            const float u1 = __shfl(acc3[1][r], cl, 64);
            const float u2 = __shfl(acc3[2][r], cl, 64);
            t[r] = (q==0)? u0 : (q==1)? u1 : u2;
        }
        rgb0 = sigmoid_f(t[0]);
        rgb1 = sigmoid_f(t[1]);
        rgb2 = sigmoid_f(t[2]);
    }

    // ======== Phase 6 (wave 3): volume integration (lane = sample) ========
    {
        const float mid = ((float)s + 0.5f) * 0.03125f;
        const float sgs = s_sig[0][sc] + s_sig[1][sc] + s_sig[2][sc];
        const float sg  = fmaxf(sgs, 0.0f);

        const float alpha = active ? (1.0f - __expf(-sg*0.03125f)) : 0.0f;
        float v = active ? (1.0f - alpha + 1e-10f) : 1.0f;
        #pragma unroll
        for (int off=1; off<64; off<<=1){
            const float up = __shfl_up(v, off, 64);
            if (lane >= off) v *= up;
        }
        float T = __shfl_up(v, 1, 64);
        if (lane==0) T = 1.0f;
        const float w = alpha*T;

        if (active) out[(size_t)NR*4 + (size_t)ray*NSMP + s] = w;

        float A0=w*rgb0, A1=w*rgb1, A2=w*rgb2, AD=w*mid;
        #pragma unroll
        for (int off=32; off>0; off>>=1){
            A0 += __shfl_down(A0, off, 64);
            A1 += __shfl_down(A1, off, 64);
            A2 += __shfl_down(A2, off, 64);
            AD += __shfl_down(AD, off, 64);
        }
        if (lane==0){
            out[(size_t)ray*3+0]=A0;
            out[(size_t)ray*3+1]=A1;
            out[(size_t)ray*3+2]=A2;
            out[(size_t)NR*3 + (size_t)ray]=AD;
        }
    }
}

// One fused prep kernel:
//  blocks [0, tileN)          : LDS-tiled mats transpose f32 [ib][32][2304] -> c4-major quad-tiled f16
//  blocks [tileN, tileN+prepN): vec regroup + frag-ordered weight prep + gelu Phi LUT
__global__ __launch_bounds__(256)
void fused_prep(const float* __restrict__ mats, const float* __restrict__ vecs,
                const float* __restrict__ w_mat, const float* __restrict__ w1,
                const float* __restrict__ w2,
                f16* __restrict__ tm, f16* __restrict__ tv,
                f16* __restrict__ wT, f16* __restrict__ w1T, f16* __restrict__ w2T16,
                f16* __restrict__ lut,
                int tileN, int vecsz){
    __shared__ float tl[32][33];
    const int bid = blockIdx.x;
    if (bid < tileN){
        const int ib   = bid / 72;
        const int pix0 = (bid % 72) * 32;
        const int tx = threadIdx.x & 31;
        const int ty = threadIdx.x >> 5;      // 0..7
        const float* src = mats + (size_t)ib*32*2304;
        #pragma unroll
        for (int t=0;t<4;t++){
            const int c = ty + t*8;
            tl[c][tx] = src[(size_t)c*2304 + pix0 + tx];
        }
        __syncthreads();
        f16* dst = tm + (size_t)ib*2304*32;
        #pragma unroll
        for (int t=0;t<4;t++){
            const int p  = pix0 + ty + t*8;   // global pixel id
            const int y  = p / 48, x = p % 48;
            const int c  = tx;                 // channel
            // [c4][qy][qx][sy][sx][8ch]
            const int o  = ((((c>>3)*24 + (y>>1))*24 + (x>>1))*4 + (y&1)*2 + (x&1))*8 + (c&7);
            dst[o] = (f16)tl[tx][ty + t*8];
        }
    } else {
        const int idx = (bid - tileN)*256 + threadIdx.x;
        if (idx < vecsz){
            // src: idx = (ib*32 + c)*48 + r  ->  dst [ib][c4][r][8ch]
            const int r  = idx % 48;
            const int c  = (idx / 48) & 31;
            const int ib = idx / (48*32);
            tv[(((size_t)ib*4 + (c>>3))*48 + r)*8 + (c&7)] = (f16)vecs[idx];
        } else if (idx < vecsz + 64*96){
            // frag-ordered wT: [(wv*3+ks)*64 + lane]*8 + e
            const int i1   = idx - vecsz;
            const int e    = i1 & 7;
            const int lane = (i1 >> 3) & 63;
            const int t    = i1 >> 9;          // 0..11
            const int ks   = t % 3;
            const int wvv  = t / 3;
            const int n = wvv*16 + (lane & 15);
            const int k = ks*32 + (lane >> 4)*8 + e;
            wT[i1] = (k < 72) ? (f16)w_mat[k*64+n] : (f16)0.0f;
        } else if (idx < vecsz + 64*96 + 64*64){
            // frag-ordered w1T: [(wv*2+ks)*64 + lane]*8 + e
            const int i2   = idx - vecsz - 64*96;
            const int e    = i2 & 7;
            const int lane = (i2 >> 3) & 63;
            const int t    = i2 >> 9;          // 0..7
            const int ks   = t & 1;
            const int wvv  = t >> 1;
            const int n = wvv*16 + (lane & 15);
            const int k = ks*32 + (lane >> 4)*8 + e;
            w1T[i2] = (f16)w1[k*64+n];
        } else if (idx < vecsz + 64*96 + 64*64 + 16*64){
            // frag-ordered w2T16: [ks*64 + lane]*8 + e
            const int i3   = idx - vecsz - 64*96 - 64*64;
            const int e    = i3 & 7;
            const int lane = (i3 >> 3) & 63;
            const int ks   = i3 >> 9;          // 0..1
            const int n = lane & 15;
            const int k = ks*32 + (lane >> 4)*8 + e;
            w2T16[i3] = (n < 3) ? (f16)w2[k*3+n] : (f16)0.0f;
        } else if (idx < vecsz + 64*96 + 64*64 + 16*64 + 1024){
            const int i4 = idx - vecsz - 64*96 - 64*64 - 16*64;
            const unsigned short bits = (unsigned short)((i4<<6) | 0x20);  // bin midpoint
            const f16 xh = __builtin_bit_cast(f16, bits);
            float m;
            if (((i4>>4)&0x1F) == 31) m = (i4 & 0x200) ? 0.0f : 1.0f;      // inf/nan bins
            else {
                const float x = (float)xh;
                m = 0.5f*(1.0f + erff(x*0.70710678118654752f));            // Phi(x)
            }
            lut[i4] = (f16)m;
        }
    }
}

extern "C" void kernel_launch(void* const* d_in, const int* in_sizes, int n_in,
                              void* d_out, int out_size, void* d_ws, size_t ws_size,
                              hipStream_t stream) {
    const float* rays_o  = (const float*)d_in[0];
    const float* rays_d  = (const float*)d_in[1];
    const float* matrixs = (const float*)d_in[2];
    const float* vectors = (const float*)d_in[3];
    const float* w_mat   = (const float*)d_in[4];
    const float* b_mat   = (const float*)d_in[5];
    const float* w1      = (const float*)d_in[6];
    const float* b1      = (const float*)d_in[7];
    const float* w2      = (const float*)d_in[8];
    const float* b2      = (const float*)d_in[9];
    float* out = (float*)d_out;

    const int B = in_sizes[2] / (3*32*48*48);
    const int R = (in_sizes[0]/3) / B;
    const int NR = B*R;

    const int matsz = 3*B*32*2304;
    const int vecsz = 3*B*32*48;
    const int wtot  = 64*96 + 64*64 + 16*64 + 1024;     // weights + Phi LUT
    const size_t need_full = ((size_t)matsz + (size_t)vecsz + (size_t)wtot)*sizeof(f16);
    const size_t need_w    = (size_t)wtot*sizeof(f16);

    const int nblk = NR;            // one block (4 waves) per ray
    const int nthr = 256;

    if (ws_size >= need_full){
        f16* tm    = (f16*)d_ws;
        f16* tv    = tm + matsz;
        f16* wT    = tv + vecsz;
        f16* w1T   = wT + 64*96;
        f16* w2T16 = w1T + 64*64;
        f16* lut   = w2T16 + 16*64;
        const int tileN = 72*3*B;
        const int smalln = vecsz + wtot;
        const int prepN  = (smalln + 255)/256;
        fused_prep<<<tileN + prepN, 256, 0, stream>>>(matrixs, vectors, w_mat, w1, w2,
                                                      tm, tv, wT, w1T, w2T16, lut, tileN, vecsz);
        render_kernel<true><<<nblk, nthr, 0, stream>>>(rays_o, rays_d, tm, tv,
            nullptr, nullptr, wT, b_mat, w1T, b1, w1, w2T16, b2, lut, out, B, R);
    } else if (ws_size >= need_w){
        f16* wT    = (f16*)d_ws;
        f16* w1T   = wT + 64*96;
        f16* w2T16 = w1T + 64*64;
        f16* lut   = w2T16 + 16*64;
        const int prepN = (wtot + 255)/256;
        fused_prep<<<prepN, 256, 0, stream>>>(nullptr, nullptr, w_mat, w1, w2,
                                              nullptr, nullptr, wT, w1T, w2T16, lut, 0, 0);
        render_kernel<false><<<nblk, nthr, 0, stream>>>(rays_o, rays_d,
            nullptr, nullptr, matrixs, vectors, wT, b_mat, w1T, b1, w1, w2T16, b2, lut, out, B, R);
    }
}

// Round 8
// 196.206 us; speedup vs baseline: 1.0825x; 1.0195x over previous
//
#include <hip/hip_runtime.h>
#include <math.h>

#define NSMP 48
#define FSTR 72    // feat row stride in f16 (72 data; 144B rows, 16B-aligned)
#define HSTR 72    // hid row stride in f16

typedef _Float16 f16;
typedef _Float16 half8 __attribute__((ext_vector_type(8)));
typedef _Float16 half4 __attribute__((ext_vector_type(4)));
typedef _Float16 h2    __attribute__((ext_vector_type(2)));
typedef float    f32x4 __attribute__((ext_vector_type(4)));

__device__ __forceinline__ float sigmoid_f(float x){
    return __builtin_amdgcn_rcpf(1.0f + __expf(-x));
}
// fast f16 gelu: Phi-table indexed by top-10 bits of the f16 value (sign+exp+4 mant)
__device__ __forceinline__ h2 gelu16x2(h2 x, const f16* __restrict__ lut16){
    const uint32_t w = __builtin_bit_cast(uint32_t, x);
    h2 m = { lut16[(w>>6) & 0x3FF], lut16[w>>22] };
    return x * m;
}
__device__ __forceinline__ f16 gelu16_1(f16 x, const f16* __restrict__ lut16){
    const uint16_t w = __builtin_bit_cast(uint16_t, x);
    return x * lut16[(w>>6) & 0x3FF];
}

// Block = ONE ray, 4 waves:
//   waves 0..2: gather mode wv (phase 1), m-tile wv of GEMM1/GEMM2, then EXIT after barrier 3
//   wave  3   : PE fold during gather, m-tile 3 of GEMM1/GEMM2, ALL of phase 5 (3 n-tiles,
//               shfl redistribution instead of LDS), volume integration. Barrier 4 removed.
//
// TR layouts (built by fused_prep):
//   mats16: [ib][c4(4)][qy(24)][qx(24)][sy(2)][sx(2)][8ch]
//           64B line = 2x2 pixel quad x 8ch (adjacent samples share quads -> low
//           per-instruction unique-line scatter); c4 planes 73KB apart (channel spread).
//   vecs16: [ib][c4(4)][row(48)][8ch]  (whole c4-plane = 12 lines; c4 stride 768B = imm offset)
//   wT    : frag-ordered [wv(4)][ks(3)][lane(64)][8]   (A-frag read = coalesced 1KB)
//   w1T   : frag-ordered [wv(4)][ks(2)][lane(64)][8]
//   w2T16 : frag-ordered [ks(2)][lane(64)][8]
//
// Gather c4-loop is software-pipelined (1-iter-ahead rotating prefetch) so the
// 6 global loads of iteration c4+1 are in flight while iteration c4's blend executes.
template<bool TR>
__global__ __launch_bounds__(256, 8)
void render_kernel(const float* __restrict__ rays_o,
                   const float* __restrict__ rays_d,
                   const f16*   __restrict__ mats16,
                   const f16*   __restrict__ vecs16,
                   const float* __restrict__ matsf,   // !TR: original f32 layout
                   const float* __restrict__ vecsf,
                   const f16*   __restrict__ wTf,
                   const float* __restrict__ g_bmat,
                   const f16*   __restrict__ w1f,
                   const float* __restrict__ g_b1,
                   const float* __restrict__ g_w1,    // f32 w1 (PE rows 64..90)
                   const f16*   __restrict__ w2f,
                   const float* __restrict__ g_b2,
                   const f16*   __restrict__ g_lut,   // [1024] f16 Phi table (from prep)
                   float* __restrict__ out, int B, int R)
{
    __shared__ __align__(16) f16   s_feat[NSMP*FSTR];   // 6912 B  feat (then gelu(h2) overlay)
    __shared__ __align__(16) f16   s_hid [NSMP*HSTR];   // 6912 B  gelu(hid)
    __shared__ __align__(16) f16   s_lut16[1024];       // 2048 B
    __shared__ float s_pe[64];                          //  256 B
    __shared__ float s_sig[3][NSMP];                    //  576 B  -> 16704 B total

    const int tid  = threadIdx.x;
    const int wv   = tid >> 6;
    const int lane = tid & 63;
    const int NR   = B*R;
    const int ray  = blockIdx.x;          // one block per ray, grid == NR
    const int b    = ray / R;

    // LUT: cooperative 2KB copy from global (precomputed in prep)
    ((half4*)s_lut16)[tid] = ((const half4*)g_lut)[tid];
    __syncthreads();                                        // barrier 0: LUT ready
    const f16* lut16 = s_lut16;

    const float dx=rays_d[ray*3+0], dy=rays_d[ray*3+1], dz=rays_d[ray*3+2];

    const int q  = lane >> 4;   // quad
    const int cl = lane & 15;   // col index within tile
    const int s  = lane;        // sample index (phases 1 & 6)
    const bool active = (s < NSMP);
    const int  sc     = active ? s : (NSMP-1);

    // ================= Phase 1: gather (wave = mode, lane = sample) =================
    if (wv < 3){
        const float ox=rays_o[ray*3+0], oy=rays_o[ray*3+1], oz=rays_o[ray*3+2];
        const int i = wv;
        const float midc = ((float)sc + 0.5f) * 0.03125f;
        const float x0c = 1.25f*(ox + dx*midc);
        const float x1c = 1.25f*(oy + dy*midc);
        const float x2c = 1.25f*(oz + dz*midc);

        // MAT_MODE = {{0,1},{2,0},{1,2}}, VEC_MODE = {2,1,0}
        const float cx = (i==0)? x0c : (i==1)? x2c : x1c;
        const float cy = (i==0)? x1c : (i==1)? x0c : x2c;
        const float cv = (i==0)? x2c : (i==1)? x1c : x0c;

        const float px = (cx+1.0f)*23.5f;
        const float py = (cy+1.0f)*23.5f;
        const float fx0 = floorf(px), fy0 = floorf(py);
        const float wx = px-fx0, wy = py-fy0;
        const int x0i = (int)fx0, y0i = (int)fy0;
        const int x1i = x0i+1,   y1i = y0i+1;

        // hoisted per-axis clamp + in-bounds
        const int  xc0 = min(max(x0i,0),47), xc1 = min(max(x1i,0),47);
        const int  yc0 = min(max(y0i,0),47), yc1 = min(max(y1i,0),47);
        const bool bx0 = (unsigned)x0i < 48u, bx1 = (unsigned)x1i < 48u;
        const bool by0 = (unsigned)y0i < 48u, by1 = (unsigned)y1i < 48u;
        const float wx1 = wx, wx0 = 1.0f-wx;
        const float wy1 = wy, wy0 = 1.0f-wy;

        float tw[4];
        tw[0] = (bx0&&by0)? wx0*wy0 : 0.0f;
        tw[1] = (bx1&&by0)? wx1*wy0 : 0.0f;
        tw[2] = (bx0&&by1)? wx0*wy1 : 0.0f;
        tw[3] = (bx1&&by1)? wx1*wy1 : 0.0f;

        // per-axis f16-offset terms for the c4-major tiled layout:
        //   off(c4=0) = (qy*24+qx)*32 + sy*16 + sx*8   (f16 units)
        const int rt0 = (yc0>>1)*768 + (yc0&1)*16;
        const int rt1 = (yc1>>1)*768 + (yc1&1)*16;
        const int ct0 = (xc0>>1)*32  + (xc0&1)*8;
        const int ct1 = (xc1>>1)*32  + (xc1&1)*8;

        // !TR linear pixel ids
        int toff[4];
        toff[0] = yc0*48+xc0; toff[1] = yc0*48+xc1;
        toff[2] = yc1*48+xc0; toff[3] = yc1*48+xc1;

        const float pv = (cv+1.0f)*23.5f;
        const float fp0 = floorf(pv);
        const float wvv = pv-fp0;
        const int ip0 = (int)fp0;
        int voff[2]; float vw[2];
        #pragma unroll
        for (int t=0;t<2;t++){
            const int pp = ip0+t;
            const bool inb = (unsigned)pp < 48u;
            voff[t] = min(max(pp,0),47);
            vw[t] = inb ? ((t)? wvv : 1.0f-wvv) : 0.0f;
        }

        float sigma = 0.0f;

        if (TR){
            const f16* pb = mats16 + ((size_t)(i*B+b))*(2304u*32u);
            const f16* vb = vecs16 + ((size_t)(i*B+b))*(48u*32u);
            const half8* t0 = (const half8*)(pb + rt0 + ct0);
            const half8* t1 = (const half8*)(pb + rt0 + ct1);
            const half8* t2 = (const half8*)(pb + rt1 + ct0);
            const half8* t3 = (const half8*)(pb + rt1 + ct1);
            const half8* v0 = (const half8*)(vb + voff[0]*8);
            const half8* v1 = (const half8*)(vb + voff[1]*8);

            const h2 tw0h = {(f16)tw[0],(f16)tw[0]};
            const h2 tw1h = {(f16)tw[1],(f16)tw[1]};
            const h2 tw2h = {(f16)tw[2],(f16)tw[2]};
            const h2 tw3h = {(f16)tw[3],(f16)tw[3]};
            const h2 vw0h = {(f16)vw[0],(f16)vw[0]};
            const h2 vw1h = {(f16)vw[1],(f16)vw[1]};

            // software-pipelined c4 loop: prefetch iteration c4+1's 6 loads
            // (plane c4 stride = 2304 half8 = 73728B; vec c4 stride = 48 half8 = 768B)
            half8 a0 = t0[0], a1 = t1[0], a2 = t2[0], a3 = t3[0];
            half8 q0 = v0[0], q1 = v1[0];
            #pragma unroll
            for (int c4=0;c4<4;c4++){
                half8 na0,na1,na2,na3,nq0,nq1;
                if (c4 < 3){
                    na0 = t0[(c4+1)*2304]; na1 = t1[(c4+1)*2304];
                    na2 = t2[(c4+1)*2304]; na3 = t3[(c4+1)*2304];
                    nq0 = v0[(c4+1)*48];   nq1 = v1[(c4+1)*48];
                }
                h2 gg[4];
                #pragma unroll
                for (int j=0;j<4;j++){
                    const h2 a0j = {a0[2*j], a0[2*j+1]};
                    const h2 a1j = {a1[2*j], a1[2*j+1]};
                    const h2 a2j = {a2[2*j], a2[2*j+1]};
                    const h2 a3j = {a3[2*j], a3[2*j+1]};
                    const h2 q0j = {q0[2*j], q0[2*j+1]};
                    const h2 q1j = {q1[2*j], q1[2*j+1]};
                    h2 pf = a0j*tw0h; pf += a1j*tw1h; pf += a2j*tw2h; pf += a3j*tw3h;
                    h2 vf = q0j*vw0h; vf += q1j*vw1h;
                    const h2 fj = pf*vf;
                    if (c4==0){
                        sigma += (float)fj[0] + (float)fj[1];
                    } else {
                        gg[j] = gelu16x2(fj, lut16);
                    }
                }
                if (c4>0 && active){
                    half8 hv = {gg[0][0],gg[0][1],gg[1][0],gg[1][1],
                                gg[2][0],gg[2][1],gg[3][0],gg[3][1]};
                    *(half8*)(s_feat + s*FSTR + i*24 + c4*8 - 8) = hv;
                }
                if (c4 < 3){
                    a0=na0; a1=na1; a2=na2; a3=na3; q0=nq0; q1=nq1;
                }
            }
        } else {
            const float* pb = matsf + ((size_t)(i*B+b))*(32u*2304u);
            const float* vb = vecsf + ((size_t)(i*B+b))*(32u*48u);
            #pragma unroll 2
            for (int c=0;c<32;c++){
                const float* fc = pb + c*2304;
                const float pf = tw[0]*fc[toff[0]] + tw[1]*fc[toff[1]]
                               + tw[2]*fc[toff[2]] + tw[3]*fc[toff[3]];
                const float* vc = vb + c*48;
                const float vf = vw[0]*vc[voff[0]] + vw[1]*vc[voff[1]];
                const float r = pf*vf;
                if (c < 8) sigma += r;
                else if (active) s_feat[s*FSTR + i*24 + c - 8] = gelu16_1((f16)r, lut16);
            }
        }
        if (active) s_sig[wv][s] = sigma;
    } else {
        // ================= Phase 3: PE fold (lane = hidden j), overlapped with gather ====
        float pe = g_b1[lane];
        const float inv_n = rsqrtf(dx*dx+dy*dy+dz*dz);
        const float vd0=dx*inv_n, vd1=dy*inv_n, vd2=dz*inv_n;
        pe += vd0*g_w1[64*64+lane] + vd1*g_w1[65*64+lane] + vd2*g_w1[66*64+lane];
        #pragma unroll 1
        for (int fq=0; fq<4; fq++){
            const float fs = (float)(1<<fq);
            float s0,c0,s1,c1,s2,c2;
            __sincosf(vd0*fs, &s0, &c0);
            __sincosf(vd1*fs, &s1, &c1);
            __sincosf(vd2*fs, &s2, &c2);
            pe += s0*g_w1[(67+fq*3+0)*64+lane];
            pe += s1*g_w1[(67+fq*3+1)*64+lane];
            pe += s2*g_w1[(67+fq*3+2)*64+lane];
            pe += c0*g_w1[(79+fq*3+0)*64+lane];
            pe += c1*g_w1[(79+fq*3+1)*64+lane];
            pe += c2*g_w1[(79+fq*3+2)*64+lane];
        }
        s_pe[lane] = pe;
    }
    __syncthreads();                                        // barrier 1: feat + pe + sig ready

    // ======== Phase 2: layer-1 GEMM  hid^T(64x48) = wT(64x96) @ feat^T(96x48), mt = wv ====
    {
        f32x4 acc[3];
        const float4 bmv = *(const float4*)(g_bmat + wv*16 + q*4);
        #pragma unroll
        for (int nt=0;nt<3;nt++){
            acc[nt][0]=bmv.x; acc[nt][1]=bmv.y; acc[nt][2]=bmv.z; acc[nt][3]=bmv.w;
        }
        #pragma unroll 1
        for (int ks=0; ks<2; ks++){
            half8 bf[3];
            #pragma unroll
            for (int nt=0;nt<3;nt++)
                bf[nt] = *(const half8*)(s_feat + (nt*16+cl)*FSTR + ks*32 + q*8);
            const half8 af = *(const half8*)(wTf + (((wv*3 + ks)*64 + lane)<<3));
            #pragma unroll
            for (int nt=0;nt<3;nt++)
                acc[nt] = __builtin_amdgcn_mfma_f32_16x16x32_f16(af, bf[nt], acc[nt], 0,0,0);
        }
        {   // ks=2: only q==0 holds real B data (k=64..71); wT rows k>=72 are zero-padded.
            half8 bf[3] = {{0,0,0,0,0,0,0,0},{0,0,0,0,0,0,0,0},{0,0,0,0,0,0,0,0}};
            if (q == 0){
                #pragma unroll
                for (int nt=0;nt<3;nt++)
                    bf[nt] = *(const half8*)(s_feat + (nt*16+cl)*FSTR + 64);
            }
            const half8 af = *(const half8*)(wTf + (((wv*3 + 2)*64 + lane)<<3));
            #pragma unroll
            for (int nt=0;nt<3;nt++)
                acc[nt] = __builtin_amdgcn_mfma_f32_16x16x32_f16(af, bf[nt], acc[nt], 0,0,0);
        }
        // gelu + store hid^T into s_hid (separate buffer -> no WAR barrier needed)
        #pragma unroll
        for (int nt=0;nt<3;nt++){
            const h2 p01 = __builtin_bit_cast(h2,
                __builtin_amdgcn_cvt_pkrtz(acc[nt][0], acc[nt][1]));
            const h2 p23 = __builtin_bit_cast(h2,
                __builtin_amdgcn_cvt_pkrtz(acc[nt][2], acc[nt][3]));
            const h2 g01 = gelu16x2(p01, lut16);
            const h2 g23 = gelu16x2(p23, lut16);
            half4 hv = {g01[0], g01[1], g23[0], g23[1]};
            *(half4*)(s_hid + (nt*16+cl)*HSTR + wv*16 + q*4) = hv;
        }
    }
    __syncthreads();                                        // barrier 2: hid ready

    // ======== Phase 4: layer-2 GEMM  h2^T(64x48) = w1T(64x64) @ hid^T(64x48), mt = wv ====
    {
        f32x4 acc2[3];
        const float4 pv4 = *(const float4*)&s_pe[wv*16 + q*4];
        #pragma unroll
        for (int nt=0;nt<3;nt++){
            acc2[nt][0]=pv4.x; acc2[nt][1]=pv4.y; acc2[nt][2]=pv4.z; acc2[nt][3]=pv4.w;
        }
        #pragma unroll 1
        for (int ks=0; ks<2; ks++){
            half8 bf[3];
            #pragma unroll
            for (int nt=0;nt<3;nt++)
                bf[nt] = *(const half8*)(s_hid + (nt*16+cl)*HSTR + ks*32 + q*8);
            const half8 af = *(const half8*)(w1f + (((wv*2 + ks)*64 + lane)<<3));
            #pragma unroll
            for (int nt=0;nt<3;nt++)
                acc2[nt] = __builtin_amdgcn_mfma_f32_16x16x32_f16(af, bf[nt], acc2[nt], 0,0,0);
        }
        // gelu(h2) -> overlay into s_feat (feat is dead after barrier 2; all waves past it)
        #pragma unroll
        for (int nt=0;nt<3;nt++){
            const h2 p01 = __builtin_bit_cast(h2,
                __builtin_amdgcn_cvt_pkrtz(acc2[nt][0], acc2[nt][1]));
            const h2 p23 = __builtin_bit_cast(h2,
                __builtin_amdgcn_cvt_pkrtz(acc2[nt][2], acc2[nt][3]));
            const h2 g01 = gelu16x2(p01, lut16);
            const h2 g23 = gelu16x2(p23, lut16);
            half4 hv = {g01[0], g01[1], g23[0], g23[1]};
            *(half4*)(s_feat + (nt*16+cl)*FSTR + wv*16 + q*4) = hv;
        }
    }
    __syncthreads();                                        // barrier 3: gelu(h2) ready

    if (wv < 3) return;   // waves 0..2 retire early; no further barriers in the block

    // ======== Phase 5 (wave 3 only): rgb^T(16x48) = w2T16(16x64) @ gelu(h2)^T, all 3 nt ====
    const float b20=g_b2[0], b21=g_b2[1], b22=g_b2[2];
    f32x4 acc3[3];
    #pragma unroll
    for (int nt=0;nt<3;nt++){
        acc3[nt][0] = (q==0)? b20 : 0.0f;
        acc3[nt][1] = (q==0)? b21 : 0.0f;
        acc3[nt][2] = (q==0)? b22 : 0.0f;
        acc3[nt][3] = 0.0f;
    }
    #pragma unroll 1
    for (int ks=0; ks<2; ks++){
        const half8 af = *(const half8*)(w2f + ((ks*64 + lane)<<3));
        #pragma unroll
        for (int nt=0;nt<3;nt++){
            const half8 bf = *(const half8*)(s_feat + (nt*16+cl)*FSTR + ks*32 + q*8);
            acc3[nt] = __builtin_amdgcn_mfma_f32_16x16x32_f16(af, bf, acc3[nt], 0,0,0);
        }
    }

    // redistribute within wave 3: lane L's sample rgb sits in lane (L&15) of tile (L>>4), rows 0..2
    float rgb0, rgb1, rgb2;
    {
        float t[3];
        #pragma unroll
        for (int r=0;r<3;r++){
            const float u0 = __shfl(acc3[0][r], cl, 64);
            const float u1 = __shfl(acc3[1][r], cl, 64);
            const float u2 = __shfl(acc3[2][r], cl, 64);
            t[r] = (q==0)? u0 : (q==1)? u1 : u2;
        }
        rgb0 = sigmoid_f(t[0]);
        rgb1 = sigmoid_f(t[1]);
        rgb2 = sigmoid_f(t[2]);
    }

    // ======== Phase 6 (wave 3): volume integration (lane = sample) ========
    {
        const float mid = ((float)s + 0.5f) * 0.03125f;
        const float sgs = s_sig[0][sc] + s_sig[1][sc] + s_sig[2][sc];
        const float sg  = fmaxf(sgs, 0.0f);

        const float alpha = active ? (1.0f - __expf(-sg*0.03125f)) : 0.0f;
        float v = active ? (1.0f - alpha + 1e-10f) : 1.0f;
        #pragma unroll
        for (int off=1; off<64; off<<=1){
            const float up = __shfl_up(v, off, 64);
            if (lane >= off) v *= up;
        }
        float T = __shfl_up(v, 1, 64);
        if (lane==0) T = 1.0f;
        const float w = alpha*T;

        if (active) out[(size_t)NR*4 + (size_t)ray*NSMP + s] = w;

        float A0=w*rgb0, A1=w*rgb1, A2=w*rgb2, AD=w*mid;
        #pragma unroll
        for (int off=32; off>0; off>>=1){
            A0 += __shfl_down(A0, off, 64);
            A1 += __shfl_down(A1, off, 64);
            A2 += __shfl_down(A2, off, 64);
            AD += __shfl_down(AD, off, 64);
        }
        if (lane==0){
            out[(size_t)ray*3+0]=A0;
            out[(size_t)ray*3+1]=A1;
            out[(size_t)ray*3+2]=A2;
            out[(size_t)NR*3 + (size_t)ray]=AD;
        }
    }
}

// One fused prep kernel:
//  blocks [0, tileN)          : LDS-tiled mats transpose f32 [ib][32][2304] -> c4-major quad-tiled f16
//                               (store phase VECTORIZED: 128 half8 16B stores/block instead of
//                                1024 scalar 2B scatter-stores -> 8x fewer store instrs)
//  blocks [tileN, tileN+prepN): vec regroup + frag-ordered weight prep + gelu Phi LUT
__global__ __launch_bounds__(256)
void fused_prep(const float* __restrict__ mats, const float* __restrict__ vecs,
                const float* __restrict__ w_mat, const float* __restrict__ w1,
                const float* __restrict__ w2,
                f16* __restrict__ tm, f16* __restrict__ tv,
                f16* __restrict__ wT, f16* __restrict__ w1T, f16* __restrict__ w2T16,
                f16* __restrict__ lut,
                int tileN, int vecsz){
    __shared__ float tl[32][33];
    const int bid = blockIdx.x;
    if (bid < tileN){
        const int ib   = bid / 72;
        const int pix0 = (bid % 72) * 32;
        const int tx = threadIdx.x & 31;
        const int ty = threadIdx.x >> 5;      // 0..7
        const float* src = mats + (size_t)ib*32*2304;
        #pragma unroll
        for (int t=0;t<4;t++){
            const int c = ty + t*8;
            tl[c][tx] = src[(size_t)c*2304 + pix0 + tx];
        }
        __syncthreads();
        f16* dst = tm + (size_t)ib*2304*32;
        // one half8 (= 8 channels of one pixel) per thread, threads 0..127
        if (threadIdx.x < 128){
            const int pl = threadIdx.x & 31;   // pixel within tile
            const int g  = threadIdx.x >> 5;   // c4 group
            const int p  = pix0 + pl;          // global pixel id
            const int y  = p / 48, x = p % 48;
            half8 hv;
            #pragma unroll
            for (int e=0;e<8;e++) hv[e] = (f16)tl[g*8+e][pl];
            // [c4][qy][qx][sy][sx][8ch]  (f16 units)
            const int o = (((g*24 + (y>>1))*24 + (x>>1))*4 + (y&1)*2 + (x&1))*8;
            *(half8*)(dst + o) = hv;
        }
    } else {
        const int idx = (bid - tileN)*256 + threadIdx.x;
        if (idx < vecsz){
            // src: idx = (ib*32 + c)*48 + r  ->  dst [ib][c4][r][8ch]
            const int r  = idx % 48;
            const int c  = (idx / 48) & 31;
            const int ib = idx / (48*32);
            tv[(((size_t)ib*4 + (c>>3))*48 + r)*8 + (c&7)] = (f16)vecs[idx];
        } else if (idx < vecsz + 64*96){
            // frag-ordered wT: [(wv*3+ks)*64 + lane]*8 + e
            const int i1   = idx - vecsz;
            const int e    = i1 & 7;
            const int lane = (i1 >> 3) & 63;
            const int t    = i1 >> 9;          // 0..11
            const int ks   = t % 3;
            const int wvv  = t / 3;
            const int n = wvv*16 + (lane & 15);
            const int k = ks*32 + (lane >> 4)*8 + e;
            wT[i1] = (k < 72) ? (f16)w_mat[k*64+n] : (f16)0.0f;
        } else if (idx < vecsz + 64*96 + 64*64){
            // frag-ordered w1T: [(wv*2+ks)*64 + lane]*8 + e
            const int i2   = idx - vecsz - 64*96;
            const int e    = i2 & 7;
            const int lane = (i2 >> 3) & 63;
            const int t    = i2 >> 9;          // 0..7
            const int ks   = t & 1;
            const int wvv  = t >> 1;
            const int n = wvv*16 + (lane & 15);
            const int k = ks*32 + (lane >> 4)*8 + e;
            w1T[i2] = (f16)w1[k*64+n];
        } else if (idx < vecsz + 64*96 + 64*64 + 16*64){
            // frag-ordered w2T16: [ks*64 + lane]*8 + e
            const int i3   = idx - vecsz - 64*96 - 64*64;
            const int e    = i3 & 7;
            const int lane = (i3 >> 3) & 63;
            const int ks   = i3 >> 9;          // 0..1
            const int n = lane & 15;
            const int k = ks*32 + (lane >> 4)*8 + e;
            w2T16[i3] = (n < 3) ? (f16)w2[k*3+n] : (f16)0.0f;
        } else if (idx < vecsz + 64*96 + 64*64 + 16*64 + 1024){
            const int i4 = idx - vecsz - 64*96 - 64*64 - 16*64;
            const unsigned short bits = (unsigned short)((i4<<6) | 0x20);  // bin midpoint
            const f16 xh = __builtin_bit_cast(f16, bits);
            float m;
            if (((i4>>4)&0x1F) == 31) m = (i4 & 0x200) ? 0.0f : 1.0f;      // inf/nan bins
            else {
                const float x = (float)xh;
                m = 0.5f*(1.0f + erff(x*0.70710678118654752f));            // Phi(x)
            }
            lut[i4] = (f16)m;
        }
    }
}

extern "C" void kernel_launch(void* const* d_in, const int* in_sizes, int n_in,
                              void* d_out, int out_size, void* d_ws, size_t ws_size,
                              hipStream_t stream) {
    const float* rays_o  = (const float*)d_in[0];
    const float* rays_d  = (const float*)d_in[1];
    const float* matrixs = (const float*)d_in[2];
    const float* vectors = (const float*)d_in[3];
    const float* w_mat   = (const float*)d_in[4];
    const float* b_mat   = (const float*)d_in[5];
    const float* w1      = (const float*)d_in[6];
    const float* b1      = (const float*)d_in[7];
    const float* w2      = (const float*)d_in[8];
    const float* b2      = (const float*)d_in[9];
    float* out = (float*)d_out;

    const int B = in_sizes[2] / (3*32*48*48);
    const int R = (in_sizes[0]/3) / B;
    const int NR = B*R;

    const int matsz = 3*B*32*2304;
    const int vecsz = 3*B*32*48;
    const int wtot  = 64*96 + 64*64 + 16*64 + 1024;     // weights + Phi LUT
    const size_t need_full = ((size_t)matsz + (size_t)vecsz + (size_t)wtot)*sizeof(f16);
    const size_t need_w    = (size_t)wtot*sizeof(f16);

    const int nblk = NR;            // one block (4 waves) per ray
    const int nthr = 256;

    if (ws_size >= need_full){
        f16* tm    = (f16*)d_ws;
        f16* tv    = tm + matsz;
        f16* wT    = tv + vecsz;
        f16* w1T   = wT + 64*96;
        f16* w2T16 = w1T + 64*64;
        f16* lut   = w2T16 + 16*64;
        const int tileN = 72*3*B;
        const int smalln = vecsz + wtot;
        const int prepN  = (smalln + 255)/256;
        fused_prep<<<tileN + prepN, 256, 0, stream>>>(matrixs, vectors, w_mat, w1, w2,
                                                      tm, tv, wT, w1T, w2T16, lut, tileN, vecsz);
        render_kernel<true><<<nblk, nthr, 0, stream>>>(rays_o, rays_d, tm, tv,
            nullptr, nullptr, wT, b_mat, w1T, b1, w1, w2T16, b2, lut, out, B, R);
    } else if (ws_size >= need_w){
        f16* wT    = (f16*)d_ws;
        f16* w1T   = wT + 64*96;
        f16* w2T16 = w1T + 64*64;
        f16* lut   = w2T16 + 16*64;
        const int prepN = (wtot + 255)/256;
        fused_prep<<<prepN, 256, 0, stream>>>(nullptr, nullptr, w_mat, w1, w2,
                                              nullptr, nullptr, wT, w1T, w2T16, lut, 0, 0);
        render_kernel<false><<<nblk, nthr, 0, stream>>>(rays_o, rays_d,
            nullptr, nullptr, matrixs, vectors, wT, b_mat, w1T, b1, w1, w2T16, b2, lut, out, B, R);
    }
}